// Round 4
// baseline (293.792 us; speedup 1.0000x reference)
//
#include <hip/hip_runtime.h>
#include <math.h>

#define BATCH 2
#define SEQ   2048
#define NH    16
#define DH    64
#define DM    1024

typedef __attribute__((ext_vector_type(8))) short bf16x8;
typedef __attribute__((ext_vector_type(8))) unsigned short u16x8;
typedef __attribute__((ext_vector_type(4))) float f32x4;

__device__ __forceinline__ unsigned short f2bf(float f) {
    union { float f; unsigned u; } v; v.f = f;
    unsigned r = v.u + 0x7FFF + ((v.u >> 16) & 1);
    return (unsigned short)(r >> 16);
}

// ---------------------------------------------------------------------------
// conv_x: x fp32 [4096][1024] -> bf16
// ---------------------------------------------------------------------------
__global__ __launch_bounds__(256) void conv_x(
    const float* __restrict__ x, unsigned short* __restrict__ xb)
{
    size_t idx = ((size_t)blockIdx.x * 256 + threadIdx.x) * 8;
    float4 a = *(const float4*)(x + idx);
    float4 b = *(const float4*)(x + idx + 4);
    u16x8 o;
    o[0] = f2bf(a.x); o[1] = f2bf(a.y); o[2] = f2bf(a.z); o[3] = f2bf(a.w);
    o[4] = f2bf(b.x); o[5] = f2bf(b.y); o[6] = f2bf(b.z); o[7] = f2bf(b.w);
    *(u16x8*)(xb + idx) = o;
}

// ---------------------------------------------------------------------------
// conv_w: transpose+convert weights to B^T bf16 layouts.
// ---------------------------------------------------------------------------
__global__ __launch_bounds__(256) void conv_w(
    const float* __restrict__ WQ, const float* __restrict__ WK,
    const float* __restrict__ WV, const float* __restrict__ WO,
    unsigned short* __restrict__ Wt, unsigned short* __restrict__ WOt)
{
    __shared__ float sT[64][68];
    const int t = blockIdx.x;
    const int tid = threadIdx.x;

    if (t < 768) {
        int m = t >> 8, rem = t & 255, h = rem >> 4, dblk = rem & 15;
        const float* W = (m == 0) ? WQ : (m == 1) ? WK : WV;
        const float* in = W + (size_t)h * 65536 + dblk * 4096;
#pragma unroll
        for (int it = 0; it < 4; it++) {
            int idx = it * 1024 + tid * 4;
            int r = idx >> 6, c = idx & 63;
            *(float4*)(&sT[r][c]) = *(const float4*)(&in[(size_t)r * 64 + c]);
        }
        __syncthreads();
        unsigned short* out = Wt + (size_t)m * 1048576 + (size_t)h * 65536 + dblk * 64;
#pragma unroll
        for (int it = 0; it < 4; it++) {
            int idx = it * 1024 + tid * 4;
            int e = idx >> 6, d0 = idx & 63;
            ushort4 o;
            unsigned short* op = (unsigned short*)&o;
#pragma unroll
            for (int j = 0; j < 4; j++) op[j] = f2bf(sT[d0 + j][e]);
            *(ushort4*)&out[(size_t)e * 1024 + d0] = o;
        }
    } else {
        int tt = t - 768, rblk = tt >> 4, cblk = tt & 15;
        const float* in = WO + (size_t)rblk * 64 * 1024 + cblk * 64;
#pragma unroll
        for (int it = 0; it < 4; it++) {
            int idx = it * 1024 + tid * 4;
            int r = idx >> 6, c = idx & 63;
            *(float4*)(&sT[r][c]) = *(const float4*)(&in[(size_t)r * 1024 + c]);
        }
        __syncthreads();
        unsigned short* out = WOt + (size_t)cblk * 64 * 1024 + rblk * 64;
#pragma unroll
        for (int it = 0; it < 4; it++) {
            int idx = it * 1024 + tid * 4;
            int d = idx >> 6, he0 = idx & 63;
            ushort4 o;
            unsigned short* op = (unsigned short*)&o;
#pragma unroll
            for (int j = 0; j < 4; j++) op[j] = f2bf(sT[he0 + j][d]);
            *(ushort4*)&out[(size_t)d * 1024 + he0] = o;
        }
    }
}

// ---------------------------------------------------------------------------
// qkv_mfma: xb [4096][1024] bf16 @ Wt[m][h][e][d] -> Q/K bf16 [B][H][S][E],
//           V written TRANSPOSED: Vt [B][H][E][S]  (feeds attn B-frags direct)
// ---------------------------------------------------------------------------
__global__ __launch_bounds__(256) void qkv_mfma(
    const unsigned short* __restrict__ xb,
    const unsigned short* __restrict__ Wt,
    const float* __restrict__ bQ, const float* __restrict__ bK,
    const float* __restrict__ bV,
    unsigned short* __restrict__ Q, unsigned short* __restrict__ K,
    unsigned short* __restrict__ Vt)
{
    __shared__ __align__(16) unsigned short sA[128 * 72];
    __shared__ __align__(16) unsigned short sB[128 * 72];

    const int rowTile = blockIdx.x;
    const int m  = blockIdx.y >> 3;
    const int hp = blockIdx.y & 7;
    const unsigned short* Wm = Wt + (size_t)m * 1048576 + (size_t)hp * 2 * 65536;

    const int tid  = threadIdx.x;
    const int w    = tid >> 6;
    const int lane = tid & 63;
    const int l15  = lane & 15;
    const int quad = lane >> 4;
    const int rw   = (w & 1) * 64;
    const int cw   = (w >> 1) * 64;
    const int rowBase = rowTile * 128;

    f32x4 acc[4][4];
#pragma unroll
    for (int i = 0; i < 4; i++)
#pragma unroll
        for (int j = 0; j < 4; j++) acc[i][j] = (f32x4){0.f, 0.f, 0.f, 0.f};

    const int sr = tid >> 3;
    const int sc = (tid & 7) * 8;

    for (int k0 = 0; k0 < DM; k0 += 64) {
        __syncthreads();
#pragma unroll
        for (int it = 0; it < 4; it++) {
            int r = it * 32 + sr;
            *(u16x8*)&sA[r * 72 + sc] =
                *(const u16x8*)&xb[(size_t)(rowBase + r) * DM + k0 + sc];
            *(u16x8*)&sB[r * 72 + sc] =
                *(const u16x8*)&Wm[(size_t)r * DM + k0 + sc];
        }
        __syncthreads();
#pragma unroll
        for (int ks = 0; ks < 2; ks++) {
            bf16x8 af[4], bf[4];
#pragma unroll
            for (int i = 0; i < 4; i++)
                af[i] = *(const bf16x8*)&sA[(rw + i * 16 + l15) * 72 + ks * 32 + quad * 8];
#pragma unroll
            for (int j = 0; j < 4; j++)
                bf[j] = *(const bf16x8*)&sB[(cw + j * 16 + l15) * 72 + ks * 32 + quad * 8];
#pragma unroll
            for (int i = 0; i < 4; i++)
#pragma unroll
                for (int j = 0; j < 4; j++)
                    acc[i][j] = __builtin_amdgcn_mfma_f32_16x16x32_bf16(
                        af[i], bf[j], acc[i][j], 0, 0, 0);
        }
    }

    if (m == 2) {
        // V: store transposed Vt[b][h][e][s], packed 4 consecutive s per store
#pragma unroll
        for (int j = 0; j < 4; j++) {
            int col = cw + j * 16 + l15;
            int h = hp * 2 + (col >> 6);
            int e = col & 63;
            float bv = bV[h * DH + e];
#pragma unroll
            for (int i = 0; i < 4; i++) {
                int row0 = rowBase + rw + i * 16 + quad * 4;
                int b = row0 >> 11, s0 = row0 & 2047;
                ushort4 o;
                unsigned short* op = (unsigned short*)&o;
#pragma unroll
                for (int r = 0; r < 4; r++) op[r] = f2bf(acc[i][j][r] + bv);
                *(ushort4*)&Vt[(((size_t)b * NH + h) * DH + e) * SEQ + s0] = o;
            }
        }
    } else {
        const float* bias = (m == 0) ? bQ : bK;
        unsigned short* Out = (m == 0) ? Q : K;
        const float scale = (m == 0) ? 0.125f : 1.0f;
#pragma unroll
        for (int j = 0; j < 4; j++) {
            int col = cw + j * 16 + l15;
            int h = hp * 2 + (col >> 6);
            int e = col & 63;
            float bv = bias[h * DH + e];
#pragma unroll
            for (int i = 0; i < 4; i++) {
#pragma unroll
                for (int r = 0; r < 4; r++) {
                    int row = rowBase + rw + i * 16 + quad * 4 + r;
                    int b = row >> 11, s = row & 2047;
                    Out[(((size_t)b * NH + h) * SEQ + s) * DH + e] =
                        f2bf((acc[i][j][r] + bv) * scale);
                }
            }
        }
    }
}

// ---------------------------------------------------------------------------
// attn_mfma v2: barrier-free k-loop.
//  - K frags AND V^T frags load straight from global (k-contiguous).
//  - register ping-pong double-buffer prefetches tile kt+1 during compute.
//  - LDS only for sP (wave-private rows; wave_barrier ordering only).
//  - blockIdx swizzle: h in low bits -> head-sharing blocks on same XCD.
// ---------------------------------------------------------------------------
__device__ __forceinline__ void load_tiles(
    const unsigned short* __restrict__ Kh,
    const unsigned short* __restrict__ Vth,
    int k0, int l15, int quad,
    bf16x8 (&kf)[8], bf16x8 (&vf)[8])
{
#pragma unroll
    for (int ks = 0; ks < 2; ks++)
#pragma unroll
        for (int sub = 0; sub < 4; sub++) {
            kf[ks * 4 + sub] = *(const bf16x8*)
                &Kh[(size_t)(k0 + sub * 16 + l15) * DH + ks * 32 + quad * 8];
            vf[ks * 4 + sub] = *(const bf16x8*)
                &Vth[(size_t)(sub * 16 + l15) * SEQ + k0 + ks * 32 + quad * 8];
        }
}

__device__ __forceinline__ void compute_tile(
    const bf16x8 (&kf)[8], const bf16x8 (&vf)[8],
    const bf16x8 (&qf)[2], unsigned short* __restrict__ sP,
    int kt, int qt, int w, int l15, int quad,
    f32x4 (&O4)[4], float (&l_p)[4])
{
    f32x4 S4[4];
#pragma unroll
    for (int s = 0; s < 4; s++) S4[s] = (f32x4){0.f, 0.f, 0.f, 0.f};
#pragma unroll
    for (int ks = 0; ks < 2; ks++)
#pragma unroll
        for (int sub = 0; sub < 4; sub++)
            S4[sub] = __builtin_amdgcn_mfma_f32_16x16x32_bf16(
                qf[ks], kf[ks * 4 + sub], S4[sub], 0, 0, 0);

    const bool diag = (kt == qt);
#pragma unroll
    for (int sub = 0; sub < 4; sub++) {
#pragma unroll
        for (int r = 0; r < 4; r++) {
            float p = __expf(S4[sub][r]);
            if (diag && (sub * 16 + l15 > w * 16 + quad * 4 + r)) p = 0.f;
            l_p[r] += p;
            sP[(w * 16 + quad * 4 + r) * 72 + sub * 16 + l15] = f2bf(p);
        }
    }
    __builtin_amdgcn_wave_barrier();

#pragma unroll
    for (int ks = 0; ks < 2; ks++) {
        bf16x8 a = *(const bf16x8*)&sP[(w * 16 + l15) * 72 + ks * 32 + quad * 8];
#pragma unroll
        for (int sub = 0; sub < 4; sub++)
            O4[sub] = __builtin_amdgcn_mfma_f32_16x16x32_bf16(
                a, vf[ks * 4 + sub], O4[sub], 0, 0, 0);
    }
    __builtin_amdgcn_wave_barrier();
}

__global__ __launch_bounds__(256) void attn_mfma(
    const unsigned short* __restrict__ Q,    // [B][H][S][E] bf16, pre-scaled
    const unsigned short* __restrict__ K,    // [B][H][S][E] bf16
    const unsigned short* __restrict__ Vt,   // [B][H][E][S] bf16
    unsigned short* __restrict__ Z)          // [B][S][H*E] bf16
{
    __shared__ __align__(16) unsigned short sP[64 * 72];

    // swizzle: h in low 4 bits -> blocks of one head land on <=2 XCDs
    const int h    = blockIdx.x & 15;
    const int b    = (blockIdx.x >> 4) & 1;
    const int pair = blockIdx.x >> 5;        // 0..15
    const int tid  = threadIdx.x;
    const int w    = tid >> 6;
    const int lane = tid & 63;
    const int l15  = lane & 15;
    const int quad = lane >> 4;

    const size_t headOff = ((size_t)b * NH + h) * SEQ * DH;
    const unsigned short* Qh  = Q  + headOff;
    const unsigned short* Kh  = K  + headOff;
    const unsigned short* Vth = Vt + headOff;   // [E][S], same size

    for (int half = 0; half < 2; half++) {
        const int qt = half ? (31 - pair) : pair;

        const unsigned short* qrow =
            Qh + (size_t)(qt * 64 + w * 16 + l15) * DH + quad * 8;
        bf16x8 qf[2];
        qf[0] = *(const bf16x8*)(qrow);
        qf[1] = *(const bf16x8*)(qrow + 32);

        f32x4 O4[4];
        float l_p[4];
#pragma unroll
        for (int s = 0; s < 4; s++) O4[s] = (f32x4){0.f, 0.f, 0.f, 0.f};
#pragma unroll
        for (int r = 0; r < 4; r++) l_p[r] = 0.f;

        bf16x8 ka[8], va[8], kb[8], vb[8];
        load_tiles(Kh, Vth, 0, l15, quad, ka, va);
        int kt = 0;
        for (;;) {
            if (kt + 1 <= qt) load_tiles(Kh, Vth, (kt + 1) * 64, l15, quad, kb, vb);
            compute_tile(ka, va, qf, sP, kt, qt, w, l15, quad, O4, l_p);
            if (++kt > qt) break;
            if (kt + 1 <= qt) load_tiles(Kh, Vth, (kt + 1) * 64, l15, quad, ka, va);
            compute_tile(kb, vb, qf, sP, kt, qt, w, l15, quad, O4, l_p);
            if (++kt > qt) break;
        }

        float rl[4];
#pragma unroll
        for (int r = 0; r < 4; r++) {
            float v = l_p[r];
            v += __shfl_xor(v, 1, 64);
            v += __shfl_xor(v, 2, 64);
            v += __shfl_xor(v, 4, 64);
            v += __shfl_xor(v, 8, 64);
            rl[r] = 1.0f / v;
        }

#pragma unroll
        for (int sub = 0; sub < 4; sub++) {
#pragma unroll
            for (int r = 0; r < 4; r++) {
                int q = qt * 64 + w * 16 + quad * 4 + r;
                int col = h * DH + sub * 16 + l15;
                Z[((size_t)b * SEQ + q) * DM + col] = f2bf(O4[sub][r] * rl[r]);
            }
        }
    }
}

// ---------------------------------------------------------------------------
// out_mfma: Zb [4096][1024] bf16 @ WOt [d][he] bf16 -> out fp32 + b_O
// ---------------------------------------------------------------------------
__global__ __launch_bounds__(256) void out_mfma(
    const unsigned short* __restrict__ Zb,
    const unsigned short* __restrict__ WOt,
    const float* __restrict__ bO,
    float* __restrict__ out)
{
    __shared__ __align__(16) unsigned short sA[64 * 72];
    __shared__ __align__(16) unsigned short sB[128 * 72];

    const int rowTile = blockIdx.x;
    const int colTile = blockIdx.y;
    const int rowBase = rowTile * 64;
    const int colBase = colTile * 128;

    const int tid  = threadIdx.x;
    const int w    = tid >> 6;
    const int lane = tid & 63;
    const int l15  = lane & 15;
    const int quad = lane >> 4;
    const int rw   = (w & 1) * 32;
    const int cw   = (w >> 1) * 64;

    f32x4 acc[2][4];
#pragma unroll
    for (int i = 0; i < 2; i++)
#pragma unroll
        for (int j = 0; j < 4; j++) acc[i][j] = (f32x4){0.f, 0.f, 0.f, 0.f};

    const int sr = tid >> 3;
    const int sc = (tid & 7) * 8;

    for (int k0 = 0; k0 < DM; k0 += 64) {
        __syncthreads();
#pragma unroll
        for (int it = 0; it < 2; it++) {
            int r = it * 32 + sr;
            *(u16x8*)&sA[r * 72 + sc] =
                *(const u16x8*)&Zb[(size_t)(rowBase + r) * DM + k0 + sc];
        }
#pragma unroll
        for (int it = 0; it < 4; it++) {
            int r = it * 32 + sr;
            *(u16x8*)&sB[r * 72 + sc] =
                *(const u16x8*)&WOt[(size_t)(colBase + r) * DM + k0 + sc];
        }
        __syncthreads();
#pragma unroll
        for (int ks = 0; ks < 2; ks++) {
            bf16x8 af[2], bf[4];
#pragma unroll
            for (int i = 0; i < 2; i++)
                af[i] = *(const bf16x8*)&sA[(rw + i * 16 + l15) * 72 + ks * 32 + quad * 8];
#pragma unroll
            for (int j = 0; j < 4; j++)
                bf[j] = *(const bf16x8*)&sB[(cw + j * 16 + l15) * 72 + ks * 32 + quad * 8];
#pragma unroll
            for (int i = 0; i < 2; i++)
#pragma unroll
                for (int j = 0; j < 4; j++)
                    acc[i][j] = __builtin_amdgcn_mfma_f32_16x16x32_bf16(
                        af[i], bf[j], acc[i][j], 0, 0, 0);
        }
    }

#pragma unroll
    for (int j = 0; j < 4; j++) {
        int col = colBase + cw + j * 16 + l15;
        float bv = bO[col];
#pragma unroll
        for (int i = 0; i < 2; i++) {
#pragma unroll
            for (int r = 0; r < 4; r++) {
                int row = rowBase + rw + i * 16 + quad * 4 + r;
                out[(size_t)row * DM + col] = acc[i][j][r] + bv;
            }
        }
    }
}

// ---------------------------------------------------------------------------
extern "C" void kernel_launch(void* const* d_in, const int* in_sizes, int n_in,
                              void* d_out, int out_size, void* d_ws, size_t ws_size,
                              hipStream_t stream)
{
    const float* x  = (const float*)d_in[0];
    const float* WQ = (const float*)d_in[1];
    const float* WK = (const float*)d_in[2];
    const float* WV = (const float*)d_in[3];
    const float* WO = (const float*)d_in[4];
    const float* bQ = (const float*)d_in[5];
    const float* bK = (const float*)d_in[6];
    const float* bV = (const float*)d_in[7];
    const float* bO = (const float*)d_in[8];
    float* out = (float*)d_out;

    const size_t M4 = 4194304;
    unsigned short* xb  = (unsigned short*)d_ws;       // 4M (reused as Zb)
    unsigned short* Wt  = xb + M4;                     // 3M
    unsigned short* WOt = Wt + 3 * 1048576;            // 1M
    unsigned short* Qw  = WOt + 1048576;               // 4M
    unsigned short* Kw  = Qw + M4;                     // 4M
    unsigned short* Vtw = Kw + M4;                     // 4M (transposed V)
    unsigned short* Zb  = xb;

    conv_x<<<2048, 256, 0, stream>>>(x, xb);
    conv_w<<<1024, 256, 0, stream>>>(WQ, WK, WV, WO, Wt, WOt);

    dim3 g1(32, 24);
    qkv_mfma<<<g1, 256, 0, stream>>>(xb, Wt, bQ, bK, bV, Qw, Kw, Vtw);

    attn_mfma<<<512, 256, 0, stream>>>(Qw, Kw, Vtw, Zb);

    dim3 g3(64, 8);
    out_mfma<<<g3, 256, 0, stream>>>(Zb, WOt, bO, out);
}

// Round 5
// 232.657 us; speedup vs baseline: 1.2628x; 1.2628x over previous
//
#include <hip/hip_runtime.h>
#include <math.h>

#define BATCH 2
#define SEQ   2048
#define NH    16
#define DH    64
#define DM    1024

typedef __attribute__((ext_vector_type(8))) short bf16x8;
typedef __attribute__((ext_vector_type(8))) unsigned short u16x8;
typedef __attribute__((ext_vector_type(4))) float f32x4;

__device__ __forceinline__ unsigned short f2bf(float f) {
    union { float f; unsigned u; } v; v.f = f;
    unsigned r = v.u + 0x7FFF + ((v.u >> 16) & 1);
    return (unsigned short)(r >> 16);
}

// ---------------------------------------------------------------------------
// conv_x: x fp32 [4096][1024] -> bf16
// ---------------------------------------------------------------------------
__global__ __launch_bounds__(256) void conv_x(
    const float* __restrict__ x, unsigned short* __restrict__ xb)
{
    size_t idx = ((size_t)blockIdx.x * 256 + threadIdx.x) * 8;
    float4 a = *(const float4*)(x + idx);
    float4 b = *(const float4*)(x + idx + 4);
    u16x8 o;
    o[0] = f2bf(a.x); o[1] = f2bf(a.y); o[2] = f2bf(a.z); o[3] = f2bf(a.w);
    o[4] = f2bf(b.x); o[5] = f2bf(b.y); o[6] = f2bf(b.z); o[7] = f2bf(b.w);
    *(u16x8*)(xb + idx) = o;
}

// ---------------------------------------------------------------------------
// conv_w: transpose+convert weights to B^T bf16 layouts.
// ---------------------------------------------------------------------------
__global__ __launch_bounds__(256) void conv_w(
    const float* __restrict__ WQ, const float* __restrict__ WK,
    const float* __restrict__ WV, const float* __restrict__ WO,
    unsigned short* __restrict__ Wt, unsigned short* __restrict__ WOt)
{
    __shared__ float sT[64][68];
    const int t = blockIdx.x;
    const int tid = threadIdx.x;

    if (t < 768) {
        int m = t >> 8, rem = t & 255, h = rem >> 4, dblk = rem & 15;
        const float* W = (m == 0) ? WQ : (m == 1) ? WK : WV;
        const float* in = W + (size_t)h * 65536 + dblk * 4096;
#pragma unroll
        for (int it = 0; it < 4; it++) {
            int idx = it * 1024 + tid * 4;
            int r = idx >> 6, c = idx & 63;
            *(float4*)(&sT[r][c]) = *(const float4*)(&in[(size_t)r * 64 + c]);
        }
        __syncthreads();
        unsigned short* out = Wt + (size_t)m * 1048576 + (size_t)h * 65536 + dblk * 64;
#pragma unroll
        for (int it = 0; it < 4; it++) {
            int idx = it * 1024 + tid * 4;
            int e = idx >> 6, d0 = idx & 63;
            ushort4 o;
            unsigned short* op = (unsigned short*)&o;
#pragma unroll
            for (int j = 0; j < 4; j++) op[j] = f2bf(sT[d0 + j][e]);
            *(ushort4*)&out[(size_t)e * 1024 + d0] = o;
        }
    } else {
        int tt = t - 768, rblk = tt >> 4, cblk = tt & 15;
        const float* in = WO + (size_t)rblk * 64 * 1024 + cblk * 64;
#pragma unroll
        for (int it = 0; it < 4; it++) {
            int idx = it * 1024 + tid * 4;
            int r = idx >> 6, c = idx & 63;
            *(float4*)(&sT[r][c]) = *(const float4*)(&in[(size_t)r * 1024 + c]);
        }
        __syncthreads();
        unsigned short* out = WOt + (size_t)cblk * 64 * 1024 + rblk * 64;
#pragma unroll
        for (int it = 0; it < 4; it++) {
            int idx = it * 1024 + tid * 4;
            int d = idx >> 6, he0 = idx & 63;
            ushort4 o;
            unsigned short* op = (unsigned short*)&o;
#pragma unroll
            for (int j = 0; j < 4; j++) op[j] = f2bf(sT[he0 + j][d]);
            *(ushort4*)&out[(size_t)d * 1024 + he0] = o;
        }
    }
}

// ---------------------------------------------------------------------------
// qkv_mfma: xb [4096][1024] bf16 @ Wt[m][h][e][d] -> Q/K bf16 [B][H][S][E],
//           V written TRANSPOSED: Vt [B][H][E][S]
// ---------------------------------------------------------------------------
__global__ __launch_bounds__(256) void qkv_mfma(
    const unsigned short* __restrict__ xb,
    const unsigned short* __restrict__ Wt,
    const float* __restrict__ bQ, const float* __restrict__ bK,
    const float* __restrict__ bV,
    unsigned short* __restrict__ Q, unsigned short* __restrict__ K,
    unsigned short* __restrict__ Vt)
{
    __shared__ __align__(16) unsigned short sA[128 * 72];
    __shared__ __align__(16) unsigned short sB[128 * 72];

    const int rowTile = blockIdx.x;
    const int m  = blockIdx.y >> 3;
    const int hp = blockIdx.y & 7;
    const unsigned short* Wm = Wt + (size_t)m * 1048576 + (size_t)hp * 2 * 65536;

    const int tid  = threadIdx.x;
    const int w    = tid >> 6;
    const int lane = tid & 63;
    const int l15  = lane & 15;
    const int quad = lane >> 4;
    const int rw   = (w & 1) * 64;
    const int cw   = (w >> 1) * 64;
    const int rowBase = rowTile * 128;

    f32x4 acc[4][4];
#pragma unroll
    for (int i = 0; i < 4; i++)
#pragma unroll
        for (int j = 0; j < 4; j++) acc[i][j] = (f32x4){0.f, 0.f, 0.f, 0.f};

    const int sr = tid >> 3;
    const int sc = (tid & 7) * 8;

    for (int k0 = 0; k0 < DM; k0 += 64) {
        __syncthreads();
#pragma unroll
        for (int it = 0; it < 4; it++) {
            int r = it * 32 + sr;
            *(u16x8*)&sA[r * 72 + sc] =
                *(const u16x8*)&xb[(size_t)(rowBase + r) * DM + k0 + sc];
            *(u16x8*)&sB[r * 72 + sc] =
                *(const u16x8*)&Wm[(size_t)r * DM + k0 + sc];
        }
        __syncthreads();
#pragma unroll
        for (int ks = 0; ks < 2; ks++) {
            bf16x8 af[4], bf[4];
#pragma unroll
            for (int i = 0; i < 4; i++)
                af[i] = *(const bf16x8*)&sA[(rw + i * 16 + l15) * 72 + ks * 32 + quad * 8];
#pragma unroll
            for (int j = 0; j < 4; j++)
                bf[j] = *(const bf16x8*)&sB[(cw + j * 16 + l15) * 72 + ks * 32 + quad * 8];
#pragma unroll
            for (int i = 0; i < 4; i++)
#pragma unroll
                for (int j = 0; j < 4; j++)
                    acc[i][j] = __builtin_amdgcn_mfma_f32_16x16x32_bf16(
                        af[i], bf[j], acc[i][j], 0, 0, 0);
        }
    }

    if (m == 2) {
#pragma unroll
        for (int j = 0; j < 4; j++) {
            int col = cw + j * 16 + l15;
            int h = hp * 2 + (col >> 6);
            int e = col & 63;
            float bv = bV[h * DH + e];
#pragma unroll
            for (int i = 0; i < 4; i++) {
                int row0 = rowBase + rw + i * 16 + quad * 4;
                int b = row0 >> 11, s0 = row0 & 2047;
                ushort4 o;
                unsigned short* op = (unsigned short*)&o;
#pragma unroll
                for (int r = 0; r < 4; r++) op[r] = f2bf(acc[i][j][r] + bv);
                *(ushort4*)&Vt[(((size_t)b * NH + h) * DH + e) * SEQ + s0] = o;
            }
        }
    } else {
        const float* bias = (m == 0) ? bQ : bK;
        unsigned short* Out = (m == 0) ? Q : K;
        const float scale = (m == 0) ? 0.125f : 1.0f;
#pragma unroll
        for (int j = 0; j < 4; j++) {
            int col = cw + j * 16 + l15;
            int h = hp * 2 + (col >> 6);
            int e = col & 63;
            float bv = bias[h * DH + e];
#pragma unroll
            for (int i = 0; i < 4; i++) {
#pragma unroll
                for (int r = 0; r < 4; r++) {
                    int row = rowBase + rw + i * 16 + quad * 4 + r;
                    int b = row >> 11, s = row & 2047;
                    Out[(((size_t)b * NH + h) * SEQ + s) * DH + e] =
                        f2bf((acc[i][j][r] + bv) * scale);
                }
            }
        }
    }
}

// ---------------------------------------------------------------------------
// attn_mfma v3: LDS-staged shared K/V + dual q-tile per block.
//  - block handles q-tiles {2i, 2i+1} of one (b,h): both consume the SAME
//    staged K/V tile and the SAME kf/vf frags -> 32 MFMA/wave per shared iter.
//  - 272 block-iterations per (b,h) (vs 528), staged 16 KB/iter coalesced.
//  - sP per tile (wave-private rows, wave_barrier only); h in low blockIdx
//    bits for XCD L2 locality; big blocks (i=15) dispatched first.
// ---------------------------------------------------------------------------
__device__ __forceinline__ void attn_tile(
    const bf16x8 (&kf)[8], const bf16x8 (&vf)[8], const bf16x8 (&qf)[2],
    unsigned short* __restrict__ sP,
    int kt, int qt, int w, int l15, int quad,
    f32x4 (&O4)[4], float (&l_p)[4])
{
    f32x4 S4[4];
#pragma unroll
    for (int s = 0; s < 4; s++) S4[s] = (f32x4){0.f, 0.f, 0.f, 0.f};
#pragma unroll
    for (int ks = 0; ks < 2; ks++)
#pragma unroll
        for (int sub = 0; sub < 4; sub++)
            S4[sub] = __builtin_amdgcn_mfma_f32_16x16x32_bf16(
                qf[ks], kf[ks * 4 + sub], S4[sub], 0, 0, 0);

    const bool diag = (kt == qt);
#pragma unroll
    for (int sub = 0; sub < 4; sub++) {
#pragma unroll
        for (int r = 0; r < 4; r++) {
            float p = __expf(S4[sub][r]);
            if (diag && (sub * 16 + l15 > w * 16 + quad * 4 + r)) p = 0.f;
            l_p[r] += p;
            sP[(w * 16 + quad * 4 + r) * 72 + sub * 16 + l15] = f2bf(p);
        }
    }
    __builtin_amdgcn_wave_barrier();

#pragma unroll
    for (int ks = 0; ks < 2; ks++) {
        bf16x8 a = *(const bf16x8*)&sP[(w * 16 + l15) * 72 + ks * 32 + quad * 8];
#pragma unroll
        for (int sub = 0; sub < 4; sub++)
            O4[sub] = __builtin_amdgcn_mfma_f32_16x16x32_bf16(
                a, vf[ks * 4 + sub], O4[sub], 0, 0, 0);
    }
    __builtin_amdgcn_wave_barrier();
}

__global__ __launch_bounds__(256) void attn_mfma(
    const unsigned short* __restrict__ Q,    // [B][H][S][E] bf16, pre-scaled
    const unsigned short* __restrict__ K,    // [B][H][S][E] bf16
    const unsigned short* __restrict__ Vt,   // [B][H][E][S] bf16
    unsigned short* __restrict__ Z)          // [B][S][H*E] bf16
{
    __shared__ __align__(16) unsigned short sK [64 * 72];
    __shared__ __align__(16) unsigned short sV [64 * 72];   // [e][k]
    __shared__ __align__(16) unsigned short sPA[64 * 72];
    __shared__ __align__(16) unsigned short sPB[64 * 72];

    const int h   = blockIdx.x & 15;
    const int b   = (blockIdx.x >> 4) & 1;
    const int i   = 15 - (blockIdx.x >> 5);   // big blocks first
    const int qtA = 2 * i;
    const int qtB = 2 * i + 1;

    const int tid  = threadIdx.x;
    const int w    = tid >> 6;
    const int lane = tid & 63;
    const int l15  = lane & 15;
    const int quad = lane >> 4;

    const size_t headOff = ((size_t)b * NH + h) * SEQ * DH;
    const unsigned short* Qh  = Q  + headOff;
    const unsigned short* Kh  = K  + headOff;
    const unsigned short* Vth = Vt + headOff;   // [E][S]

    // Q frags for both tiles
    const unsigned short* qrowA =
        Qh + (size_t)(qtA * 64 + w * 16 + l15) * DH + quad * 8;
    const unsigned short* qrowB =
        Qh + (size_t)(qtB * 64 + w * 16 + l15) * DH + quad * 8;
    bf16x8 qA[2], qB[2];
    qA[0] = *(const bf16x8*)(qrowA);  qA[1] = *(const bf16x8*)(qrowA + 32);
    qB[0] = *(const bf16x8*)(qrowB);  qB[1] = *(const bf16x8*)(qrowB + 32);

    f32x4 OA[4], OB[4];
    float lA[4], lB[4];
#pragma unroll
    for (int s = 0; s < 4; s++) {
        OA[s] = (f32x4){0.f, 0.f, 0.f, 0.f};
        OB[s] = (f32x4){0.f, 0.f, 0.f, 0.f};
    }
#pragma unroll
    for (int r = 0; r < 4; r++) { lA[r] = 0.f; lB[r] = 0.f; }

    const int r0 = tid >> 3;          // staging row 0..31
    const int c0 = (tid & 7) * 8;     // staging col (elems)

    for (int kt = 0; kt <= qtB; kt++) {
        const int k0 = kt * 64;
        __syncthreads();   // all waves done reading prev tile frags
        *(u16x8*)&sK[r0 * 72 + c0] =
            *(const u16x8*)&Kh[(size_t)(k0 + r0) * DH + c0];
        *(u16x8*)&sK[(r0 + 32) * 72 + c0] =
            *(const u16x8*)&Kh[(size_t)(k0 + r0 + 32) * DH + c0];
        *(u16x8*)&sV[r0 * 72 + c0] =
            *(const u16x8*)&Vth[(size_t)r0 * SEQ + k0 + c0];
        *(u16x8*)&sV[(r0 + 32) * 72 + c0] =
            *(const u16x8*)&Vth[(size_t)(r0 + 32) * SEQ + k0 + c0];
        __syncthreads();   // tile staged

        bf16x8 kf[8], vf[8];
#pragma unroll
        for (int ks = 0; ks < 2; ks++)
#pragma unroll
            for (int sub = 0; sub < 4; sub++) {
                kf[ks * 4 + sub] = *(const bf16x8*)
                    &sK[(sub * 16 + l15) * 72 + ks * 32 + quad * 8];
                vf[ks * 4 + sub] = *(const bf16x8*)
                    &sV[(sub * 16 + l15) * 72 + ks * 32 + quad * 8];
            }

        if (kt <= qtA)
            attn_tile(kf, vf, qA, sPA, kt, qtA, w, l15, quad, OA, lA);
        attn_tile(kf, vf, qB, sPB, kt, qtB, w, l15, quad, OB, lB);
    }

    // epilogue: denominators + stores for both tiles
#pragma unroll
    for (int half = 0; half < 2; half++) {
        const int qt = half ? qtB : qtA;
        f32x4* O4 = half ? OB : OA;
        float* l_p = half ? lB : lA;
        float rl[4];
#pragma unroll
        for (int r = 0; r < 4; r++) {
            float v = l_p[r];
            v += __shfl_xor(v, 1, 64);
            v += __shfl_xor(v, 2, 64);
            v += __shfl_xor(v, 4, 64);
            v += __shfl_xor(v, 8, 64);
            rl[r] = 1.0f / v;
        }
#pragma unroll
        for (int sub = 0; sub < 4; sub++) {
#pragma unroll
            for (int r = 0; r < 4; r++) {
                int q = qt * 64 + w * 16 + quad * 4 + r;
                int col = h * DH + sub * 16 + l15;
                Z[((size_t)b * SEQ + q) * DM + col] = f2bf(O4[sub][r] * rl[r]);
            }
        }
    }
}

// ---------------------------------------------------------------------------
// out_mfma: Zb [4096][1024] bf16 @ WOt [d][he] bf16 -> out fp32 + b_O
// ---------------------------------------------------------------------------
__global__ __launch_bounds__(256) void out_mfma(
    const unsigned short* __restrict__ Zb,
    const unsigned short* __restrict__ WOt,
    const float* __restrict__ bO,
    float* __restrict__ out)
{
    __shared__ __align__(16) unsigned short sA[64 * 72];
    __shared__ __align__(16) unsigned short sB[128 * 72];

    const int rowTile = blockIdx.x;
    const int colTile = blockIdx.y;
    const int rowBase = rowTile * 64;
    const int colBase = colTile * 128;

    const int tid  = threadIdx.x;
    const int w    = tid >> 6;
    const int lane = tid & 63;
    const int l15  = lane & 15;
    const int quad = lane >> 4;
    const int rw   = (w & 1) * 32;
    const int cw   = (w >> 1) * 64;

    f32x4 acc[2][4];
#pragma unroll
    for (int i = 0; i < 2; i++)
#pragma unroll
        for (int j = 0; j < 4; j++) acc[i][j] = (f32x4){0.f, 0.f, 0.f, 0.f};

    const int sr = tid >> 3;
    const int sc = (tid & 7) * 8;

    for (int k0 = 0; k0 < DM; k0 += 64) {
        __syncthreads();
#pragma unroll
        for (int it = 0; it < 2; it++) {
            int r = it * 32 + sr;
            *(u16x8*)&sA[r * 72 + sc] =
                *(const u16x8*)&Zb[(size_t)(rowBase + r) * DM + k0 + sc];
        }
#pragma unroll
        for (int it = 0; it < 4; it++) {
            int r = it * 32 + sr;
            *(u16x8*)&sB[r * 72 + sc] =
                *(const u16x8*)&WOt[(size_t)(colBase + r) * DM + k0 + sc];
        }
        __syncthreads();
#pragma unroll
        for (int ks = 0; ks < 2; ks++) {
            bf16x8 af[2], bf[4];
#pragma unroll
            for (int i = 0; i < 2; i++)
                af[i] = *(const bf16x8*)&sA[(rw + i * 16 + l15) * 72 + ks * 32 + quad * 8];
#pragma unroll
            for (int j = 0; j < 4; j++)
                bf[j] = *(const bf16x8*)&sB[(cw + j * 16 + l15) * 72 + ks * 32 + quad * 8];
#pragma unroll
            for (int i = 0; i < 2; i++)
#pragma unroll
                for (int j = 0; j < 4; j++)
                    acc[i][j] = __builtin_amdgcn_mfma_f32_16x16x32_bf16(
                        af[i], bf[j], acc[i][j], 0, 0, 0);
        }
    }

#pragma unroll
    for (int j = 0; j < 4; j++) {
        int col = colBase + cw + j * 16 + l15;
        float bv = bO[col];
#pragma unroll
        for (int i = 0; i < 2; i++) {
#pragma unroll
            for (int r = 0; r < 4; r++) {
                int row = rowBase + rw + i * 16 + quad * 4 + r;
                out[(size_t)row * DM + col] = acc[i][j][r] + bv;
            }
        }
    }
}

// ---------------------------------------------------------------------------
extern "C" void kernel_launch(void* const* d_in, const int* in_sizes, int n_in,
                              void* d_out, int out_size, void* d_ws, size_t ws_size,
                              hipStream_t stream)
{
    const float* x  = (const float*)d_in[0];
    const float* WQ = (const float*)d_in[1];
    const float* WK = (const float*)d_in[2];
    const float* WV = (const float*)d_in[3];
    const float* WO = (const float*)d_in[4];
    const float* bQ = (const float*)d_in[5];
    const float* bK = (const float*)d_in[6];
    const float* bV = (const float*)d_in[7];
    const float* bO = (const float*)d_in[8];
    float* out = (float*)d_out;

    const size_t M4 = 4194304;
    unsigned short* xb  = (unsigned short*)d_ws;       // 4M (reused as Zb)
    unsigned short* Wt  = xb + M4;                     // 3M
    unsigned short* WOt = Wt + 3 * 1048576;            // 1M
    unsigned short* Qw  = WOt + 1048576;               // 4M
    unsigned short* Kw  = Qw + M4;                     // 4M
    unsigned short* Vtw = Kw + M4;                     // 4M (transposed V)
    unsigned short* Zb  = xb;

    conv_x<<<2048, 256, 0, stream>>>(x, xb);
    conv_w<<<1024, 256, 0, stream>>>(WQ, WK, WV, WO, Wt, WOt);

    dim3 g1(32, 24);
    qkv_mfma<<<g1, 256, 0, stream>>>(xb, Wt, bQ, bK, bV, Qw, Kw, Vtw);

    attn_mfma<<<512, 256, 0, stream>>>(Qw, Kw, Vtw, Zb);

    dim3 g3(64, 8);
    out_mfma<<<g3, 256, 0, stream>>>(Zb, WOt, bO, out);
}